// Round 15
// baseline (207.132 us; speedup 1.0000x reference)
//
#include <hip/hip_runtime.h>
#include <math.h>

#define Bb 8
#define Hh 8
#define LQ 2048
#define LK 2048
#define Dd 64
#define Uu 40
#define NCH 64
#define CHUNK (LK / NCH)   // 32
#define NSPL 8
#define CK (LK / NSPL)     // 256 keys per split-K chunk
#define SM_BLOCKS (Bb * (LQ / 8))        // 2048 sampleM blocks
#define PART_BLOCKS (Bb * NCH / 2)       // 256 V-chunk-sum blocks (2 chunks each)
#define ATTN_BLOCKS (Bb * Hh * NSPL)     // 512
#define SCAN_BLOCKS (Bb * NCH / 2)       // 256 (2 chunks each)

typedef float f32x4 __attribute__((ext_vector_type(4)));
typedef short bf16x8 __attribute__((ext_vector_type(8)));

__device__ __forceinline__ short f2bf(float x) {
    unsigned u = __float_as_uint(x);
    unsigned r = u + 0x7fffu + ((u >> 16) & 1u);   // RNE
    return (short)(r >> 16);
}

__device__ __forceinline__ bf16x8 pack8(float4 a, float4 b) {
    bf16x8 r;
    r[0] = f2bf(a.x); r[1] = f2bf(a.y); r[2] = f2bf(a.z); r[3] = f2bf(a.w);
    r[4] = f2bf(b.x); r[5] = f2bf(b.y); r[6] = f2bf(b.z); r[7] = f2bf(b.w);
    return r;
}

// ---------------- L1: sampleM gather (first) + V chunk sums (tail) ----------------
__global__ __launch_bounds__(256) void k_main(
    const float* __restrict__ Qp, const float* __restrict__ Kp,
    const int* __restrict__ idxs, const float* __restrict__ Vp,
    float* __restrict__ M, float* __restrict__ part)
{
    int t = threadIdx.x;

    if (blockIdx.x >= SM_BLOCKS) {
        int bid2 = blockIdx.x - SM_BLOCKS;
        int b = bid2 >> 5;
        int c = (bid2 & 31) * 2 + (t >> 7);
        int h = (t >> 4) & 7, d4 = (t & 15) * 4;

        const float* vb = Vp + ((size_t)(b * LK + c * CHUNK)) * 512 + h * 64 + d4;
        float4 s = make_float4(0.f, 0.f, 0.f, 0.f);
#pragma unroll 4
        for (int l = 0; l < CHUNK; ++l) {
            float4 v = *reinterpret_cast<const float4*>(vb + (size_t)l * 512);
            s.x += v.x; s.y += v.y; s.z += v.z; s.w += v.w;
        }
        int bh = b * 8 + h;
        *reinterpret_cast<float4*>(&part[(size_t)(bh * NCH + c) * Dd + d4]) = s;
        return;
    }

    int b  = blockIdx.x & 7;      // b-major: round-robin XCD dispatch pins K[b] per XCD L2
    int qt = blockIdx.x >> 3;
    int lane = t & 63, wave = t >> 6;

    __shared__ int sIdx[8 * Uu];
    for (int i = t; i < 8 * Uu; i += 256)
        sIdx[i] = idxs[(qt * 8) * Uu + i];
    __syncthreads();

    const size_t HD = 512;
    const float* Kb = Kp + (size_t)b * LK * HD + lane * 4;

#pragma unroll
    for (int i = 0; i < 2; ++i) {
        int lq = wave * 2 + i;
        int q  = qt * 8 + lq;
        const int* sI = &sIdx[lq * Uu];
#pragma unroll
        for (int ph = 0; ph < 2; ++ph) {
            f32x4 qa = __builtin_nontemporal_load(
                reinterpret_cast<const f32x4*>(
                    Qp + ((size_t)b * LQ + q) * HD + ph * 256) + lane);

            float mx = -INFINITY, sm = 0.f;
#pragma unroll 8
            for (int s = 0; s < Uu; ++s) {
                int kidx = sI[s];
                f32x4 kv = *reinterpret_cast<const f32x4*>(
                    Kb + (size_t)kidx * HD + ph * 256);
                float p = qa[0] * kv[0] + qa[1] * kv[1]
                        + qa[2] * kv[2] + qa[3] * kv[3];
                p += __shfl_xor(p, 1, 64);
                p += __shfl_xor(p, 2, 64);
                p += __shfl_xor(p, 4, 64);
                p += __shfl_xor(p, 8, 64);
                mx = fmaxf(mx, p); sm += p;
            }
            if ((lane & 15) == 0) {
                int h = ph * 4 + (lane >> 4);
                __builtin_nontemporal_store(
                    mx - sm * (1.0f / Uu), &M[((b * 8 + h) << 11) + q]);
            }
        }
    }
}

// ---------------- L2: topk (blocks 0..63, sorted output) || cumsum-scan (64..319) -------
__global__ __launch_bounds__(256) void k_topk_scan(
    const float* __restrict__ M, int* __restrict__ Mtop,
    const float* __restrict__ Vp, const float* __restrict__ part,
    float* __restrict__ out, unsigned* __restrict__ cnt)
{
    int t = threadIdx.x;

    if (blockIdx.x < Bb * Hh) {
        int bh = blockIdx.x;
        if (t == 0) cnt[bh] = 0;          // re-arm split-K counter for kernel 3
        __shared__ float Ml[LQ];
        for (int j = t; j < LQ; j += 256)
            Ml[j] = M[bh * LQ + j];
        __syncthreads();
        if (t >= 64) return;              // wave 0 only past this point (no more barriers)
        int lane = t;

        float lv = -INFINITY; int li = LQ;
        for (int j = 0; j < 32; ++j) {
            int idx = lane + 64 * j;
            float x = Ml[idx];
            if (x > lv) { lv = x; li = idx; }
        }

        int myp = 0;                      // lane u keeps the u-th pick
        for (int u = 0; u < Uu; ++u) {
            float v = lv; int id = li;
#pragma unroll
            for (int off = 32; off > 0; off >>= 1) {
                float ov = __shfl_xor(v, off, 64);
                int   oi = __shfl_xor(id, off, 64);
                if (ov > v || (ov == v && oi < id)) { v = ov; id = oi; }
            }
            if (u == lane) myp = id;      // all lanes agree on id
            if ((id & 63) == lane) {      // owner invalidates + rescans its column
                Ml[id] = -INFINITY;
                lv = -INFINITY; li = LQ;
                for (int j = 0; j < 32; ++j) {
                    int idx = lane + 64 * j;
                    float x = Ml[idx];
                    if (x > lv) { lv = x; li = idx; }
                }
            }
        }

        // rank-sort the 40 picks ascending by position (indices distinct -> no ties)
        int rank = 0;
        for (int j = 0; j < Uu; ++j) {
            int pj = __shfl(myp, j, 64);
            rank += (pj < myp && lane < Uu) ? 1 : 0;
        }
        if (lane < Uu) Mtop[bh * Uu + rank] = myp;
        return;
    }

    // ---- cumsum over all rows (self-computed prefix; independent of topk) ----
    int bid2 = blockIdx.x - Bb * Hh;
    int b = bid2 >> 5;
    int ch = (bid2 & 31) * 2 + (t >> 7);
    int t2 = t & 127;
    int h = t2 >> 4, d4 = (t2 & 15) * 4;
    int bh = b * 8 + h;

    float4 run = make_float4(0.f, 0.f, 0.f, 0.f);
    for (int cc = 0; cc < ch; ++cc) {
        float4 p4 = *reinterpret_cast<const float4*>(
            &part[(size_t)(bh * NCH + cc) * Dd + d4]);
        run.x += p4.x; run.y += p4.y; run.z += p4.z; run.w += p4.w;
    }

    int l0 = ch * CHUNK;
    const float* vb = Vp + ((size_t)(b * LK + l0)) * 512 + h * 64 + d4;
    float* ob = out + ((size_t)(b * LQ + l0)) * 512 + h * 64 + d4;
#pragma unroll 4
    for (int l = 0; l < CHUNK; ++l) {
        float4 v = *reinterpret_cast<const float4*>(vb + (size_t)l * 512);
        run.x += v.x; run.y += v.y; run.z += v.z; run.w += v.w;
        *reinterpret_cast<float4*>(ob + (size_t)l * 512) = run;
    }
}

// ---------------- L3: attn_part (MFMA, sorted-causal skip) + last-arriver fixup ----------
__global__ __launch_bounds__(256) void k_attn_fixup(
    const float* __restrict__ Qp, const float* __restrict__ Kp,
    const float* __restrict__ Vp, const int* __restrict__ Mtop,
    float* __restrict__ pacc, float* __restrict__ pl,
    unsigned* __restrict__ cnt, float* __restrict__ out)
{
    int t = threadIdx.x;
    int bh = blockIdx.x >> 3;
    int c  = blockIdx.x & (NSPL - 1);
    int b = bh >> 3, h = bh & 7;
    int lane = t & 63, w = t >> 6;
    int col = lane & 15, hi = lane >> 4;

    __shared__ int sP[48];
    __shared__ __align__(16) short sPl[2][48][80];
    __shared__ float sL[4][48];
    __shared__ int isLast;

    if (t < 48) sP[t] = (t < Uu) ? Mtop[bh * Uu + t] : -1;
    __syncthreads();

    const int pmax = sP[Uu - 1];                       // sorted ascending
    const int qmax0 = sP[15], qmax1 = sP[31];          // per-q-block causal limits

    bf16x8 qf[3][2];
#pragma unroll
    for (int qb = 0; qb < 3; ++qb) {
        int q = qb * 16 + col;
        int row = sP[q];
#pragma unroll
        for (int ks = 0; ks < 2; ++ks) {
            const float* qp = Qp + (((size_t)b * LQ + max(row, 0)) * Hh + h) * Dd
                              + ks * 32 + hi * 8;
            float4 x = *reinterpret_cast<const float4*>(qp);
            float4 y = *reinterpret_cast<const float4*>(qp + 4);
            bf16x8 f = pack8(x, y);
            if (row < 0) f = (bf16x8)(short)0;
            qf[qb][ks] = f;
        }
    }

    f32x4 oacc[3];
    float lsum[3];
#pragma unroll
    for (int qb = 0; qb < 3; ++qb) { oacc[qb] = (f32x4)0.f; lsum[qb] = 0.f; }

    for (int tt = 0; tt < CK / 64; ++tt) {
        int k0 = c * CK + tt * 64;
        if (pmax < k0) break;
        int pb = tt & 1;
        int qblo = (k0 <= qmax0) ? 0 : ((k0 <= qmax1) ? 1 : 2);

        bf16x8 af[2];
#pragma unroll
        for (int ks = 0; ks < 2; ++ks) {
            const float* kp = Kp + (((size_t)b * LK + k0 + 16 * w + col) * Hh + h) * Dd
                              + ks * 32 + hi * 8;
            float4 x = *reinterpret_cast<const float4*>(kp);
            float4 y = *reinterpret_cast<const float4*>(kp + 4);
            af[ks] = pack8(x, y);
        }

#pragma unroll
        for (int qb = 0; qb < 3; ++qb) {
            if (qb < qblo) continue;
            f32x4 s = (f32x4)0.f;
            s = __builtin_amdgcn_mfma_f32_16x16x32_bf16(af[0], qf[qb][0], s, 0, 0, 0);
            s = __builtin_amdgcn_mfma_f32_16x16x32_bf16(af[1], qf[qb][1], s, 0, 0, 0);

            int p = sP[qb * 16 + col];
            int kbase = k0 + 16 * w + hi * 4;
            float e0 = (kbase + 0 <= p) ? __expf(s[0] * 0.125f) : 0.f;
            float e1 = (kbase + 1 <= p) ? __expf(s[1] * 0.125f) : 0.f;
            float e2 = (kbase + 2 <= p) ? __expf(s[2] * 0.125f) : 0.f;
            float e3 = (kbase + 3 <= p) ? __expf(s[3] * 0.125f) : 0.f;
            lsum[qb] += (e0 + e1) + (e2 + e3);

            int q = qb * 16 + col;
            int kl = 16 * w + hi * 4;
            unsigned p01 = (unsigned)(unsigned short)f2bf(e0)
                         | ((unsigned)(unsigned short)f2bf(e1) << 16);
            unsigned p23 = (unsigned)(unsigned short)f2bf(e2)
                         | ((unsigned)(unsigned short)f2bf(e3) << 16);
            *reinterpret_cast<unsigned*>(&sPl[pb][q][kl])     = p01;
            *reinterpret_cast<unsigned*>(&sPl[pb][q][kl + 2]) = p23;
        }
        __syncthreads();     // single barrier per tile (double-buffered P)

#pragma unroll
        for (int ks = 0; ks < 2; ++ks) {
            const float* vb = Vp + (((size_t)b * LK + k0 + ks * 32 + hi * 8) * Hh + h) * Dd
                              + 16 * w + col;
            float4 x, y;
            x.x = vb[0];       x.y = vb[512];      x.z = vb[1024];     x.w = vb[1536];
            y.x = vb[2048];    y.y = vb[2560];     y.z = vb[3072];     y.w = vb[3584];
            bf16x8 vf = pack8(x, y);
#pragma unroll
            for (int qb = 0; qb < 3; ++qb) {
                if (qb < qblo) continue;
                bf16x8 pf = *reinterpret_cast<const bf16x8*>(
                    &sPl[pb][qb * 16 + col][ks * 32 + hi * 8]);
                oacc[qb] = __builtin_amdgcn_mfma_f32_16x16x32_bf16(pf, vf, oacc[qb], 0, 0, 0);
            }
        }
    }

#pragma unroll
    for (int qb = 0; qb < 3; ++qb) {
#pragma unroll
        for (int r = 0; r < 4; ++r) {
            int q = qb * 16 + hi * 4 + r;
            if (q < Uu)
                pacc[(((size_t)bh * NSPL + c) * Uu + q) * Dd + 16 * w + col] = oacc[qb][r];
        }
        lsum[qb] += __shfl_xor(lsum[qb], 16, 64);
        lsum[qb] += __shfl_xor(lsum[qb], 32, 64);
        if (lane < 16) sL[w][qb * 16 + lane] = lsum[qb];
    }
    __syncthreads();
    if (t < Uu)
        pl[((size_t)bh * NSPL + c) * Uu + t] =
            sL[0][t] + sL[1][t] + sL[2][t] + sL[3][t];

    // ---- last-arriver fixup: 8th block of this bh combines + overwrites selected rows ----
    __threadfence();                               // release pacc/pl writes (device scope)
    __syncthreads();                               // all threads' writes fenced
    if (t == 0) isLast = (atomicAdd(&cnt[bh], 1u) == NSPL - 1) ? 1 : 0;
    __syncthreads();
    if (!isLast) return;
    __threadfence();                               // acquire other blocks' writes

#pragma unroll
    for (int uu = 0; uu < Uu / 4; ++uu) {          // 4 waves x 10 rows
        int u = w * (Uu / 4) + uu;
        float A = 0.f, L = 0.f;
#pragma unroll
        for (int cc = 0; cc < NSPL; ++cc) {
            A += pacc[(((size_t)bh * NSPL + cc) * Uu + u) * Dd + lane];
            L += pl[((size_t)bh * NSPL + cc) * Uu + u];
        }
        int p = sP[u];
        out[(((size_t)b * LQ + p) * Hh + h) * Dd + lane] = A / L;
    }
}

extern "C" void kernel_launch(void* const* d_in, const int* in_sizes, int n_in,
                              void* d_out, int out_size, void* d_ws, size_t ws_size,
                              hipStream_t stream) {
    const float* Qp   = (const float*)d_in[0];
    const float* Kp   = (const float*)d_in[1];
    const float* Vp   = (const float*)d_in[2];
    const int*   idxs = (const int*)d_in[3];
    float* out = (float*)d_out;

    char* w = (char*)d_ws;
    float*    M    = (float*)(w);                 // 512K
    int*      Mtop = (int*)  (w + 512 * 1024);    // 16K
    float*    part = (float*)(w + 528 * 1024);    // 1M
    float*    pacc = (float*)(w + 1552 * 1024);   // 5M
    float*    pl   = (float*)(w + 6672 * 1024);   // 80K
    unsigned* cnt  = (unsigned*)(w + 6752 * 1024);// 256B (64 bh counters)

    k_main<<<SM_BLOCKS + PART_BLOCKS, 256, 0, stream>>>(Qp, Kp, idxs, Vp, M, part);
    k_topk_scan<<<Bb * Hh + SCAN_BLOCKS, 256, 0, stream>>>(M, Mtop, Vp, part, out, cnt);
    k_attn_fixup<<<ATTN_BLOCKS, 256, 0, stream>>>(Qp, Kp, Vp, Mtop, pacc, pl, cnt, out);
}

// Round 16
// 137.677 us; speedup vs baseline: 1.5045x; 1.5045x over previous
//
#include <hip/hip_runtime.h>
#include <math.h>

#define Bb 8
#define Hh 8
#define LQ 2048
#define LK 2048
#define Dd 64
#define Uu 40
#define NCH 64
#define CHUNK (LK / NCH)   // 32
#define NSPL 8
#define CK (LK / NSPL)     // 256 keys per split-K chunk
#define SM_BLOCKS (Bb * (LQ / 8))        // 2048 sampleM blocks
#define PART_BLOCKS (Bb * NCH / 2)       // 256 V-chunk-sum blocks (2 chunks each)
#define ATTN_BLOCKS (Bb * Hh * NSPL)     // 512
#define SCAN_BLOCKS (Bb * NCH / 2)       // 256 (2 chunks each)

typedef float f32x4 __attribute__((ext_vector_type(4)));
typedef short bf16x8 __attribute__((ext_vector_type(8)));

__device__ __forceinline__ short f2bf(float x) {
    unsigned u = __float_as_uint(x);
    unsigned r = u + 0x7fffu + ((u >> 16) & 1u);   // RNE
    return (short)(r >> 16);
}

__device__ __forceinline__ bf16x8 pack8(float4 a, float4 b) {
    bf16x8 r;
    r[0] = f2bf(a.x); r[1] = f2bf(a.y); r[2] = f2bf(a.z); r[3] = f2bf(a.w);
    r[4] = f2bf(b.x); r[5] = f2bf(b.y); r[6] = f2bf(b.z); r[7] = f2bf(b.w);
    return r;
}

// ---------------- L1: sampleM gather (first) + V chunk sums (tail) ----------------
// sampleM at 95% of the per-CU L1-return-BW wall (61 of 64 B/cyc/CU) — final form.
__global__ __launch_bounds__(256) void k_main(
    const float* __restrict__ Qp, const float* __restrict__ Kp,
    const int* __restrict__ idxs, const float* __restrict__ Vp,
    float* __restrict__ M, float* __restrict__ part)
{
    int t = threadIdx.x;

    if (blockIdx.x >= SM_BLOCKS) {
        int bid2 = blockIdx.x - SM_BLOCKS;
        int b = bid2 >> 5;
        int c = (bid2 & 31) * 2 + (t >> 7);
        int h = (t >> 4) & 7, d4 = (t & 15) * 4;

        const float* vb = Vp + ((size_t)(b * LK + c * CHUNK)) * 512 + h * 64 + d4;
        float4 s = make_float4(0.f, 0.f, 0.f, 0.f);
#pragma unroll 4
        for (int l = 0; l < CHUNK; ++l) {
            float4 v = *reinterpret_cast<const float4*>(vb + (size_t)l * 512);
            s.x += v.x; s.y += v.y; s.z += v.z; s.w += v.w;
        }
        int bh = b * 8 + h;
        *reinterpret_cast<float4*>(&part[(size_t)(bh * NCH + c) * Dd + d4]) = s;
        return;
    }

    int b  = blockIdx.x & 7;      // b-major: round-robin XCD dispatch pins K[b] per XCD L2
    int qt = blockIdx.x >> 3;
    int lane = t & 63, wave = t >> 6;

    __shared__ int sIdx[8 * Uu];
    for (int i = t; i < 8 * Uu; i += 256)
        sIdx[i] = idxs[(qt * 8) * Uu + i];
    __syncthreads();

    const size_t HD = 512;
    const float* Kb = Kp + (size_t)b * LK * HD + lane * 4;

#pragma unroll
    for (int i = 0; i < 2; ++i) {
        int lq = wave * 2 + i;
        int q  = qt * 8 + lq;
        const int* sI = &sIdx[lq * Uu];
#pragma unroll
        for (int ph = 0; ph < 2; ++ph) {
            f32x4 qa = __builtin_nontemporal_load(
                reinterpret_cast<const f32x4*>(
                    Qp + ((size_t)b * LQ + q) * HD + ph * 256) + lane);

            float mx = -INFINITY, sm = 0.f;
#pragma unroll 8
            for (int s = 0; s < Uu; ++s) {
                int kidx = sI[s];
                f32x4 kv = *reinterpret_cast<const f32x4*>(
                    Kb + (size_t)kidx * HD + ph * 256);
                float p = qa[0] * kv[0] + qa[1] * kv[1]
                        + qa[2] * kv[2] + qa[3] * kv[3];
                p += __shfl_xor(p, 1, 64);
                p += __shfl_xor(p, 2, 64);
                p += __shfl_xor(p, 4, 64);
                p += __shfl_xor(p, 8, 64);
                mx = fmaxf(mx, p); sm += p;
            }
            if ((lane & 15) == 0) {
                int h = ph * 4 + (lane >> 4);
                __builtin_nontemporal_store(
                    mx - sm * (1.0f / Uu), &M[((b * 8 + h) << 11) + q]);
            }
        }
    }
}

// ---------------- L2: topk (blocks 0..63, sorted output) || cumsum-scan (64..319) -------
__global__ __launch_bounds__(256) void k_topk_scan(
    const float* __restrict__ M, int* __restrict__ Mtop,
    const float* __restrict__ Vp, const float* __restrict__ part,
    float* __restrict__ out)
{
    int t = threadIdx.x;

    if (blockIdx.x < Bb * Hh) {
        int bh = blockIdx.x;
        __shared__ float Ml[LQ];
        for (int j = t; j < LQ; j += 256)
            Ml[j] = M[bh * LQ + j];
        __syncthreads();
        if (t >= 64) return;              // wave 0 only (no barriers past this point)
        int lane = t;

        float lv = -INFINITY; int li = LQ;
        for (int j = 0; j < 32; ++j) {
            int idx = lane + 64 * j;
            float x = Ml[idx];
            if (x > lv) { lv = x; li = idx; }
        }

        int myp = 0;                      // lane u keeps the u-th pick
        for (int u = 0; u < Uu; ++u) {
            float v = lv; int id = li;
#pragma unroll
            for (int off = 32; off > 0; off >>= 1) {
                float ov = __shfl_xor(v, off, 64);
                int   oi = __shfl_xor(id, off, 64);
                if (ov > v || (ov == v && oi < id)) { v = ov; id = oi; }
            }
            if (u == lane) myp = id;      // all lanes agree on id
            if ((id & 63) == lane) {      // owner invalidates + rescans its column
                Ml[id] = -INFINITY;
                lv = -INFINITY; li = LQ;
                for (int j = 0; j < 32; ++j) {
                    int idx = lane + 64 * j;
                    float x = Ml[idx];
                    if (x > lv) { lv = x; li = idx; }
                }
            }
        }

        // rank-sort the 40 picks ascending by position (indices distinct -> no ties)
        int rank = 0;
        for (int j = 0; j < Uu; ++j) {
            int pj = __shfl(myp, j, 64);
            rank += (pj < myp && lane < Uu) ? 1 : 0;
        }
        if (lane < Uu) Mtop[bh * Uu + rank] = myp;
        return;
    }

    // ---- cumsum over all rows (self-computed prefix; independent of topk) ----
    int bid2 = blockIdx.x - Bb * Hh;
    int b = bid2 >> 5;
    int ch = (bid2 & 31) * 2 + (t >> 7);
    int t2 = t & 127;
    int h = t2 >> 4, d4 = (t2 & 15) * 4;
    int bh = b * 8 + h;

    float4 run = make_float4(0.f, 0.f, 0.f, 0.f);
    for (int cc = 0; cc < ch; ++cc) {
        float4 p4 = *reinterpret_cast<const float4*>(
            &part[(size_t)(bh * NCH + cc) * Dd + d4]);
        run.x += p4.x; run.y += p4.y; run.z += p4.z; run.w += p4.w;
    }

    int l0 = ch * CHUNK;
    const float* vb = Vp + ((size_t)(b * LK + l0)) * 512 + h * 64 + d4;
    float* ob = out + ((size_t)(b * LQ + l0)) * 512 + h * 64 + d4;
#pragma unroll 4
    for (int l = 0; l < CHUNK; ++l) {
        float4 v = *reinterpret_cast<const float4*>(vb + (size_t)l * 512);
        run.x += v.x; run.y += v.y; run.z += v.z; run.w += v.w;
        *reinterpret_cast<float4*>(ob + (size_t)l * 512) = run;
    }
}

// ---------------- L3: split-K attn via bf16 MFMA — strided tiles + V prefetch ----------
// Block c handles tiles {c, c+8, c+16, c+24} so all blocks see the same causal-skip
// distribution (balanced). V raw loads issued BEFORE QK/exp so latency hides under compute.
__global__ __launch_bounds__(256) void k_attn(
    const float* __restrict__ Qp, const float* __restrict__ Kp,
    const float* __restrict__ Vp, const int* __restrict__ Mtop,
    float* __restrict__ pacc, float* __restrict__ pl)
{
    int t = threadIdx.x;
    int bh = blockIdx.x >> 3;
    int c  = blockIdx.x & (NSPL - 1);
    int b = bh >> 3, h = bh & 7;
    int lane = t & 63, w = t >> 6;
    int col = lane & 15, hi = lane >> 4;

    __shared__ int sP[48];
    __shared__ __align__(16) short sPl[2][48][80];
    __shared__ float sL[4][48];

    if (t < 48) sP[t] = (t < Uu) ? Mtop[bh * Uu + t] : -1;
    __syncthreads();

    const int pmax = sP[Uu - 1];                       // sorted ascending
    const int qmax0 = sP[15], qmax1 = sP[31];          // per-q-block causal limits

    bf16x8 qf[3][2];
#pragma unroll
    for (int qb = 0; qb < 3; ++qb) {
        int q = qb * 16 + col;
        int row = sP[q];
#pragma unroll
        for (int ks = 0; ks < 2; ++ks) {
            const float* qp = Qp + (((size_t)b * LQ + max(row, 0)) * Hh + h) * Dd
                              + ks * 32 + hi * 8;
            float4 x = *reinterpret_cast<const float4*>(qp);
            float4 y = *reinterpret_cast<const float4*>(qp + 4);
            bf16x8 f = pack8(x, y);
            if (row < 0) f = (bf16x8)(short)0;
            qf[qb][ks] = f;
        }
    }

    f32x4 oacc[3];
    float lsum[3];
#pragma unroll
    for (int qb = 0; qb < 3; ++qb) { oacc[qb] = (f32x4)0.f; lsum[qb] = 0.f; }

#pragma unroll 1
    for (int j = 0; j < LK / 64 / NSPL; ++j) {         // 4 strided tiles
        int k0 = (c + NSPL * j) * 64;
        if (k0 > pmax) break;                          // k0 increases with j
        int pb = j & 1;
        int qblo = (k0 <= qmax0) ? 0 : ((k0 <= qmax1) ? 1 : 2);

        // ---- issue K-tile loads
        bf16x8 af[2];
#pragma unroll
        for (int ks = 0; ks < 2; ++ks) {
            const float* kp = Kp + (((size_t)b * LK + k0 + 16 * w + col) * Hh + h) * Dd
                              + ks * 32 + hi * 8;
            float4 x = *reinterpret_cast<const float4*>(kp);
            float4 y = *reinterpret_cast<const float4*>(kp + 4);
            af[ks] = pack8(x, y);
        }

        // ---- V prefetch: issue raw loads now; latency hides under QK/exp below
        float vx[2][8];
#pragma unroll
        for (int ks = 0; ks < 2; ++ks) {
            const float* vb = Vp + (((size_t)b * LK + k0 + ks * 32 + hi * 8) * Hh + h) * Dd
                              + 16 * w + col;
#pragma unroll
            for (int jj = 0; jj < 8; ++jj)
                vx[ks][jj] = vb[(size_t)jj * 512];
        }

#pragma unroll
        for (int qb = 0; qb < 3; ++qb) {
            if (qb < qblo) continue;
            f32x4 s = (f32x4)0.f;
            s = __builtin_amdgcn_mfma_f32_16x16x32_bf16(af[0], qf[qb][0], s, 0, 0, 0);
            s = __builtin_amdgcn_mfma_f32_16x16x32_bf16(af[1], qf[qb][1], s, 0, 0, 0);

            int p = sP[qb * 16 + col];
            int kbase = k0 + 16 * w + hi * 4;
            float e0 = (kbase + 0 <= p) ? __expf(s[0] * 0.125f) : 0.f;
            float e1 = (kbase + 1 <= p) ? __expf(s[1] * 0.125f) : 0.f;
            float e2 = (kbase + 2 <= p) ? __expf(s[2] * 0.125f) : 0.f;
            float e3 = (kbase + 3 <= p) ? __expf(s[3] * 0.125f) : 0.f;
            lsum[qb] += (e0 + e1) + (e2 + e3);

            int q = qb * 16 + col;
            int kl = 16 * w + hi * 4;
            unsigned p01 = (unsigned)(unsigned short)f2bf(e0)
                         | ((unsigned)(unsigned short)f2bf(e1) << 16);
            unsigned p23 = (unsigned)(unsigned short)f2bf(e2)
                         | ((unsigned)(unsigned short)f2bf(e3) << 16);
            *reinterpret_cast<unsigned*>(&sPl[pb][q][kl])     = p01;
            *reinterpret_cast<unsigned*>(&sPl[pb][q][kl + 2]) = p23;
        }
        __syncthreads();     // single barrier per tile (double-buffered P)

#pragma unroll
        for (int ks = 0; ks < 2; ++ks) {
            float4 x = make_float4(vx[ks][0], vx[ks][1], vx[ks][2], vx[ks][3]);
            float4 y = make_float4(vx[ks][4], vx[ks][5], vx[ks][6], vx[ks][7]);
            bf16x8 vf = pack8(x, y);
#pragma unroll
            for (int qb = 0; qb < 3; ++qb) {
                if (qb < qblo) continue;
                bf16x8 pf = *reinterpret_cast<const bf16x8*>(
                    &sPl[pb][qb * 16 + col][ks * 32 + hi * 8]);
                oacc[qb] = __builtin_amdgcn_mfma_f32_16x16x32_bf16(pf, vf, oacc[qb], 0, 0, 0);
            }
        }
    }

#pragma unroll
    for (int qb = 0; qb < 3; ++qb) {
#pragma unroll
        for (int r = 0; r < 4; ++r) {
            int q = qb * 16 + hi * 4 + r;
            if (q < Uu)
                pacc[(((size_t)bh * NSPL + c) * Uu + q) * Dd + 16 * w + col] = oacc[qb][r];
        }
        lsum[qb] += __shfl_xor(lsum[qb], 16, 64);
        lsum[qb] += __shfl_xor(lsum[qb], 32, 64);
        if (lane < 16) sL[w][qb * 16 + lane] = lsum[qb];
    }
    __syncthreads();
    if (t < Uu)
        pl[((size_t)bh * NSPL + c) * Uu + t] =
            sL[0][t] + sL[1][t] + sL[2][t] + sL[3][t];
}

// ---------------- L4: overwrite selected rows with combined attention ----------------
__global__ __launch_bounds__(256) void k_fixup(
    const int* __restrict__ Mtop, const float* __restrict__ pacc,
    const float* __restrict__ pl, float* __restrict__ out)
{
    int gid = blockIdx.x * 4 + (threadIdx.x >> 6);   // one wave per (bh,u)
    int lane = threadIdx.x & 63;
    int bh = gid / Uu, u = gid % Uu;
    int b = bh >> 3, h = bh & 7;
    int p = Mtop[bh * Uu + u];

    float A = 0.f, L = 0.f;
#pragma unroll
    for (int cc = 0; cc < NSPL; ++cc) {
        A += pacc[(((size_t)bh * NSPL + cc) * Uu + u) * Dd + lane];
        L += pl[((size_t)bh * NSPL + cc) * Uu + u];
    }
    out[(((size_t)b * LQ + p) * Hh + h) * Dd + lane] = A / L;
}

extern "C" void kernel_launch(void* const* d_in, const int* in_sizes, int n_in,
                              void* d_out, int out_size, void* d_ws, size_t ws_size,
                              hipStream_t stream) {
    const float* Qp   = (const float*)d_in[0];
    const float* Kp   = (const float*)d_in[1];
    const float* Vp   = (const float*)d_in[2];
    const int*   idxs = (const int*)d_in[3];
    float* out = (float*)d_out;

    char* w = (char*)d_ws;
    float* M    = (float*)(w);                 // 512K
    int*   Mtop = (int*)  (w + 512 * 1024);    // 16K
    float* part = (float*)(w + 528 * 1024);    // 1M
    float* pacc = (float*)(w + 1552 * 1024);   // 5M
    float* pl   = (float*)(w + 6672 * 1024);   // 80K

    k_main<<<SM_BLOCKS + PART_BLOCKS, 256, 0, stream>>>(Qp, Kp, idxs, Vp, M, part);
    k_topk_scan<<<Bb * Hh + SCAN_BLOCKS, 256, 0, stream>>>(M, Mtop, Vp, part, out);
    k_attn<<<ATTN_BLOCKS, 256, 0, stream>>>(Qp, Kp, Vp, Mtop, pacc, pl);
    k_fixup<<<Bb * Hh * Uu / 4, 256, 0, stream>>>(Mtop, pacc, pl, out);
}